// Round 10
// baseline (683.741 us; speedup 1.0000x reference)
//
#include <hip/hip_runtime.h>
#include <hip/hip_bf16.h>
#include <cstdint>
#include <cstddef>

#define KD 512

// ---- workspace byte offsets ----
#define OFF_CN   0u           // 4096 f32 coarse codebook norms
#define OFF_FN   16384u       // 8192 f32 fine codebook norms
#define OFF_ZN   49152u       // 8192 f32 z-coarse row norms
#define OFF_RN   81920u       // 8192 f32 residual row norms
#define OFF_LOSS 114688u      // 1 f32 loss accumulator + 1 u32 done-counter
#define OFF_AMC  114944u      // 8192 u64 coarse argmin keys
#define OFF_AMF  180480u      // 8192 u64 fine argmin keys
#define OFF_CEH  246016u      // 4096x512 bf16 coarse emb hi (FRAG layout)
#define OFF_CEL  4440320u     // 4096x512 bf16 coarse emb lo (FRAG layout)
#define OFF_FEH  8634624u     // 8192x512 bf16 fine emb hi (FRAG layout)
#define OFF_FEL  17023232u    // 8192x512 bf16 fine emb lo (FRAG layout)
#define OFF_ZCH  25411840u    // 8192x512 bf16 z-coarse hi (row-major); REUSED as f32 residual after coarse VQ
#define OFF_ZCL  33800448u
#define OFF_RH   42189056u    // 8192x512 bf16 residual hi (row-major)
#define OFF_RL   50577664u    // (unused)
#define OFF_W1H  58966272u    // 512x512 bf16 w_c2f hi (row-major)
#define OFF_W1L  59490560u
#define OFF_W2H  60014848u
#define OFF_W2L  60539136u
#define OFF_H    61063424u    // 8192x512 f32; REUSED as block-keys during VQ stages
#define OFF_INFL 77840640u    // 8192x512 bf16
// total = 86,229,248 bytes

// frag layout: 16B chunk index = ((row>>4)*16 + (k>>5))*64 + lane,
// lane = (row&15) | (((k>>3)&3)<<4); chunk holds elems k..k+7 of row.

typedef __attribute__((ext_vector_type(8))) short bf16x8;
typedef __attribute__((ext_vector_type(4))) float f32x4;
typedef unsigned long long u64;

__device__ __forceinline__ bf16x8 as_bf16x8(int4 v) {
  union { int4 i; bf16x8 b; } u; u.i = v; return u.b;
}

__device__ __forceinline__ void gl_lds16(const void* g, void* l) {
  __builtin_amdgcn_global_load_lds(
      (const __attribute__((address_space(1))) void*)g,
      (__attribute__((address_space(3))) void*)l, 16, 0, 0);
}

__device__ __forceinline__ float block_sum(float v, float* sred) {
#pragma unroll
  for (int off = 32; off > 0; off >>= 1) v += __shfl_down(v, off, 64);
  if ((threadIdx.x & 63) == 0) sred[threadIdx.x >> 6] = v;
  __syncthreads();
  float r = sred[0] + sred[1] + sred[2] + sred[3];
  __syncthreads();
  return r;
}

__device__ __forceinline__ float sigmoidf_(float x) { return 1.0f / (1.0f + expf(-x)); }

__device__ __forceinline__ void split_bf16(float v, __hip_bfloat16* hi, __hip_bfloat16* lo) {
  __hip_bfloat16 h = __float2bfloat16(v);
  *hi = h;
  *lo = __float2bfloat16(v - __bfloat162float(h));
}

__device__ __forceinline__ unsigned enc_sortable(float f) {
  unsigned u = __float_as_uint(f);
  return (u & 0x80000000u) ? ~u : (u | 0x80000000u);
}
__device__ __forceinline__ float dec_sortable(unsigned ub) {
  unsigned o = (ub & 0x80000000u) ? (ub & 0x7fffffffu) : ~ub;
  return __uint_as_float(o);
}
__device__ __forceinline__ u64 umin64(u64 a, u64 b) { return a < b ? a : b; }
__device__ __forceinline__ u64 umax64(u64 a, u64 b) { return a > b ? a : b; }

// merge two sorted triples (a1<=a2<=a3, b1<=b2<=b3) -> top-3 of union in a
__device__ __forceinline__ void merge3(u64& a1, u64& a2, u64& a3, u64 b1, u64 b2, u64 b3) {
  u64 p = umax64(a1, b1);
  u64 q = umin64(a2, b2);
  u64 r = umax64(a2, b2);
  u64 s = umin64(a3, b3);
  u64 m1 = umin64(a1, b1);
  u64 m2 = umin64(p, q);
  u64 m3 = umin64(umin64(umax64(p, q), r), s);
  a1 = m1; a2 = m2; a3 = m3;
}

// ---- prep: norms + splits. Codebooks -> FRAG layout (hi+lo); zc -> row-major hi only;
// weights -> row-major hi+lo. Norm reduction order UNCHANGED (tie-grid — R1).
// R10 change: frag-pack reads the row from LDS (values staged by the norm phase)
// instead of re-reading global — bit-identical f32s, kills the 2nd global read. ----
__global__ __launch_bounds__(256) void prep(
    const float* __restrict__ ce, const float* __restrict__ fe, const float* __restrict__ z,
    const float* __restrict__ w1, const float* __restrict__ w2,
    float* __restrict__ cn, float* __restrict__ fn, float* __restrict__ zn,
    __hip_bfloat16* __restrict__ ceH, __hip_bfloat16* __restrict__ ceL,
    __hip_bfloat16* __restrict__ feH, __hip_bfloat16* __restrict__ feL,
    __hip_bfloat16* __restrict__ zcH,
    __hip_bfloat16* __restrict__ w1H, __hip_bfloat16* __restrict__ w1L,
    __hip_bfloat16* __restrict__ w2H, __hip_bfloat16* __restrict__ w2L,
    float* __restrict__ lossp) {
  __shared__ float sred[4];
  __shared__ float srow_[512];
  const int b = blockIdx.x, t = threadIdx.x;
  const float* src;
  float* nd = nullptr;
  __hip_bfloat16 *dh = nullptr, *dl = nullptr;
  int fragMode = 0, hiOnly = 0;
  size_t row;
  if (b < 4096) {
    row = b; src = ce + row * KD; nd = cn + row; dh = ceH; dl = ceL; fragMode = 1;
  } else if (b < 12288) {
    row = b - 4096; src = fe + row * KD; nd = fn + row; dh = feH; dl = feL; fragMode = 1;
  } else if (b < 20480) {
    row = b - 12288; src = z + row * 1024; nd = zn + row; dh = zcH; hiOnly = 1;
  } else if (b < 20992) {
    row = b - 20480; src = w1 + row * KD; dh = w1H; dl = w1L;
  } else {
    row = b - 20992; src = w2 + row * KD; dh = w2H; dl = w2L;
  }
  float acc = 0.0f;
  if (fragMode) {
    float v0 = src[t], v1 = src[t + 256];
    srow_[t] = v0;          // stage for the pack phase (visible after block_sum's syncs)
    srow_[t + 256] = v1;
    acc = v0 * v0 + v1 * v1;
  } else {
#pragma unroll
    for (int j = 0; j < 2; ++j) {
      int c = t + j * 256;
      float v = src[c];
      acc += v * v;
      __hip_bfloat16 h, l;
      split_bf16(v, &h, &l);
      dh[row * KD + c] = h;
      if (!hiOnly) dl[row * KD + c] = l;
    }
  }
  if (nd) {
    float s = block_sum(acc, sred);
    if (t == 0) nd[0] = s;
  } else {
    __syncthreads();  // keep barrier count uniform (block_sum has syncs)
    __syncthreads();
  }
  if (fragMode && t < 64) {
    // thread t: elems [8t, 8t+8) from LDS -> one 16B chunk each for hi/lo
    union { int4 i; __hip_bfloat16 s[8]; } ph, pl;
#pragma unroll
    for (int j = 0; j < 8; ++j) {
      float v = srow_[8 * t + j];
      split_bf16(v, &ph.s[j], &pl.s[j]);
    }
    const int chunkIdx = (int)(((row >> 4) * 16 + (t >> 2)) * 64 +
                               ((size_t)((t & 3) << 4) | (row & 15)));
    ((int4*)dh)[chunkIdx] = ph.i;
    ((int4*)dl)[chunkIdx] = pl.i;
  }
  if (b == 20480 && t == 0) { lossp[0] = 0.0f; ((unsigned*)lossp)[1] = 0u; }
}

// ---- VQ v10 (R6/R8, proven best @132us fine): 256 codes x 128 queries per block.
// A+B staged via global_load_lds into 3-deep LDS rings, 2 chunks ahead; one
// raw s_barrier per iter; counted vmcnt(6) (one chunk = 6 DMAs/wave), drained
// only at i=15. Hazards audited R5/R6. NATIVE mapping keeps B L2-resident.
__global__ __launch_bounds__(256, 2) void vq10(
    const int4* __restrict__ AfH,
    const __hip_bfloat16* __restrict__ Bh,
    const float* __restrict__ cn,
    u64* __restrict__ bkeys) {   // [8192][gridDim.y][3]
  __shared__ __align__(16) int4 sA[3][1024];                // 16KB/slot (256 rows x 32k)
  __shared__ __align__(16) __hip_bfloat16 sB[3][128 * 32];  // 8KB/slot
  const int t = threadIdx.x;
  const int w = t >> 6, l = t & 63;

  const int bx = blockIdx.x;
  const int by = blockIdx.y;
  const int rowTile = by << 8;  // 256 codes
  const int colTile = bx << 7;  // 128 queries
  const int NB = gridDim.y;

  // B staging (geometry proven v7-v10): wave w stages query rows [32w,32w+32);
  // linear LDS dest, pre-swizzled global source chunk.
  const int rl = l >> 2;
  const int sbp = (l & 3) ^ ((l >> 3) & 3);
  const size_t gOff0 = (size_t)(colTile + (w << 5) + rl) * KD + (sbp << 3);
  const size_t gOff1 = gOff0 + (size_t)16 * KD;
  const int lOffB0 = (w << 5) << 5;     // elements
  const int lOffB1 = lOffB0 + (16 << 5);

  // A staging: wave w stages row-groups 4w..4w+3 (of 16 per block).
  const int rtg = rowTile >> 4;
  const int aS0 = ((rtg + 4 * w + 0) << 10) + l;
  const int aS1 = ((rtg + 4 * w + 1) << 10) + l;
  const int aS2 = ((rtg + 4 * w + 2) << 10) + l;
  const int aS3 = ((rtg + 4 * w + 3) << 10) + l;

  const int fr = l & 15;
  const int q = l >> 4;

  // wave w computes codes [64w, 64w+64) x all 128 queries: acc[mt 0..3][nt 0..7]
  f32x4 acc[4][8];
#pragma unroll
  for (int i = 0; i < 4; ++i)
#pragma unroll
    for (int j = 0; j < 8; ++j) acc[i][j] = (f32x4){0.f, 0.f, 0.f, 0.f};

#define STAGE(ck) do {                                                   \
    const int sl_ = (ck) % 3;                                            \
    gl_lds16(AfH + aS0 + ((ck) << 6), &sA[sl_][(4 * w + 0) << 6]);       \
    gl_lds16(AfH + aS1 + ((ck) << 6), &sA[sl_][(4 * w + 1) << 6]);       \
    gl_lds16(AfH + aS2 + ((ck) << 6), &sA[sl_][(4 * w + 2) << 6]);       \
    gl_lds16(AfH + aS3 + ((ck) << 6), &sA[sl_][(4 * w + 3) << 6]);       \
    gl_lds16(Bh + gOff0 + ((size_t)(ck) << 5), &sB[sl_][lOffB0]);        \
    gl_lds16(Bh + gOff1 + ((size_t)(ck) << 5), &sB[sl_][lOffB1]);        \
  } while (0)

  // prologue: stage chunks 0,1 -> slots 0,1; 12 DMAs in flight per wave.
  STAGE(0);
  STAGE(1);
  __builtin_amdgcn_sched_barrier(0);

#pragma unroll
  for (int i = 0; i < 16; ++i) {
    // chunk-i DMAs landed (oldest 6 of <=12 outstanding) + prev iter reads done
    if (i < 15) asm volatile("s_waitcnt vmcnt(6) lgkmcnt(0)" ::: "memory");
    else        asm volatile("s_waitcnt vmcnt(0) lgkmcnt(0)" ::: "memory");
    __builtin_amdgcn_s_barrier();
    __builtin_amdgcn_sched_barrier(0);
    if (i + 2 < 16) STAGE(i + 2);   // overwrites slot (i-1)%3: safe
    __builtin_amdgcn_sched_barrier(0);

    const int cb = i % 3;
    bf16x8 afh[4], bfh[8];
#pragma unroll
    for (int mt = 0; mt < 4; ++mt)
      afh[mt] = as_bf16x8(sA[cb][((4 * w) + mt) * 64 + l]);
#pragma unroll
    for (int nt = 0; nt < 8; ++nt) {
      const int rB = (nt << 4) + fr;
      const int o = (rB << 5) + ((q ^ ((rB >> 1) & 3)) << 3);
      bfh[nt] = *(const bf16x8*)(sB[cb] + o);
    }
    __builtin_amdgcn_s_setprio(1);
#pragma unroll
    for (int mt = 0; mt < 4; ++mt)
#pragma unroll
      for (int nt = 0; nt < 8; ++nt)
        acc[mt][nt] = __builtin_amdgcn_mfma_f32_16x16x32_bf16(afh[mt], bfh[nt], acc[mt][nt], 0, 0, 0);
    __builtin_amdgcn_s_setprio(0);
  }
#undef STAGE

  // epilogue: per query, top-3 over this block's 256 codes.
  u64 tk1[8], tk2[8], tk3[8];
#pragma unroll
  for (int nt = 0; nt < 8; ++nt) {
    u64 t1 = ~0ULL, t2 = ~0ULL, t3 = ~0ULL;
#pragma unroll
    for (int mt = 0; mt < 4; ++mt) {
#pragma unroll
      for (int reg = 0; reg < 4; ++reg) {
        const int code = rowTile + (w << 6) + (mt << 4) + (q << 2) + reg;
        float d = cn[code] - 2.0f * acc[mt][nt][reg];
        u64 key = ((u64)enc_sortable(d) << 32) | (u64)(unsigned)code;
        if (key < t1) { t3 = t2; t2 = t1; t1 = key; }
        else if (key < t2) { t3 = t2; t2 = key; }
        else if (key < t3) { t3 = key; }
      }
    }
    // merge across the 4 q-lanes holding the same query (fr)
#pragma unroll
    for (int off = 16; off <= 32; off <<= 1) {
      u64 b1 = __shfl_xor(t1, off, 64);
      u64 b2 = __shfl_xor(t2, off, 64);
      u64 b3 = __shfl_xor(t3, off, 64);
      merge3(t1, t2, t3, b1, b2, b3);
    }
    tk1[nt] = t1; tk2[nt] = t2; tk3[nt] = t3;
  }

  // cross-wave merge: all 4 waves cover the same 128 queries (codes stacked).
  __syncthreads();  // all LDS reads/DMAs done; reuse sA as key buffer (12KB)
  u64* sk = (u64*)sA;
  if (w > 0 && l < 16) {
#pragma unroll
    for (int nt = 0; nt < 8; ++nt) {
      const int o = (((w << 3) + nt) * 16 + fr) * 3;
      sk[o] = tk1[nt]; sk[o + 1] = tk2[nt]; sk[o + 2] = tk3[nt];
    }
  }
  __syncthreads();
  if (w == 0 && l < 16) {
#pragma unroll
    for (int nt = 0; nt < 8; ++nt) {
      u64 t1 = tk1[nt], t2 = tk2[nt], t3 = tk3[nt];
#pragma unroll
      for (int wv = 1; wv < 4; ++wv) {
        const int o = (((wv << 3) + nt) * 16 + fr) * 3;
        merge3(t1, t2, t3, sk[o], sk[o + 1], sk[o + 2]);
      }
      const int query = colTile + (nt << 4) + fr;
      const size_t bo = ((size_t)query * NB + by) * 3;
      bkeys[bo] = t1; bkeys[bo + 1] = t2; bkeys[bo + 2] = t3;
    }
  }
}

// ---- rescue: per query, gather block top-3 keys, exact-f32 rescore all
// candidates within delta of the approximate min; write final argmin key.
// Exact d replicates the reference's arithmetic: (xn + cn) - 2*dot at
// magnitude ~512 (see R1 post-mortem — tie-grid must match). ----
__global__ __launch_bounds__(256) void rescue(
    const u64* __restrict__ bkeys, int NB3,
    const float* __restrict__ Q, int qStride,
    const float* __restrict__ Cb,
    const float* __restrict__ qn, const float* __restrict__ cnorm,
    float dscale, u64* __restrict__ am) {
  const int wv = threadIdx.x >> 6, l = threadIdx.x & 63;
  const int qi = (blockIdx.x << 2) + wv;
  const u64* kq = bkeys + (size_t)qi * NB3;
  u64 kk[3];
#pragma unroll
  for (int j = 0; j < 3; ++j) {
    const int idx = l + (j << 6);
    kk[j] = (idx < NB3) ? kq[idx] : ~0ULL;
  }
  u64 kmin = umin64(kk[0], umin64(kk[1], kk[2]));
#pragma unroll
  for (int off = 32; off > 0; off >>= 1) kmin = umin64(kmin, __shfl_xor(kmin, off, 64));
  const float xnv = qn[qi];
  const float dmin = dec_sortable((unsigned)(kmin >> 32));
  const float thr = dmin + dscale * sqrtf(xnv) + 0.01f;
  const u64 thrKey = ((u64)enc_sortable(thr) << 32) | 0xffffffffULL;

  const float* qrow = Q + (size_t)qi * qStride;
  const float4 qa = *(const float4*)(qrow + (l << 3));
  const float4 qb = *(const float4*)(qrow + (l << 3) + 4);
  float bestD = 3.4e38f;
  int bestC = 0x7fffffff;
#pragma unroll
  for (int j = 0; j < 3; ++j) {
    bool pend = kk[j] <= thrKey;
    u64 mask;
    while ((mask = __ballot(pend)) != 0ULL) {
      const int src = __ffsll((unsigned long long)mask) - 1;
      const u64 key = __shfl(kk[j], src, 64);
      if (l == src) pend = false;
      const int code = (int)(unsigned)(key & 0xffffffffULL);
      const float* crow = Cb + (size_t)code * KD;
      const float4 ca = *(const float4*)(crow + (l << 3));
      const float4 cb = *(const float4*)(crow + (l << 3) + 4);
      float dt = qa.x * ca.x + qa.y * ca.y + qa.z * ca.z + qa.w * ca.w +
                 qb.x * cb.x + qb.y * cb.y + qb.z * cb.z + qb.w * cb.w;
#pragma unroll
      for (int off = 32; off > 0; off >>= 1) dt += __shfl_xor(dt, off, 64);
      const float d = (xnv + cnorm[code]) - 2.0f * dt;
      if (d < bestD || (d == bestD && code < bestC)) { bestD = d; bestC = code; }
    }
  }
  if (l == 0) am[qi] = ((u64)enc_sortable(bestD) << 32) | (unsigned)bestC;
}

// ---- MLP GEMM (3-pass hi/lo): A = gathered codebook rows (frag), B = weights.
// MLP1 only — output feeds the fine-VQ query (residual): bf16x3 required. ----
__global__ __launch_bounds__(256) void mlp6(
    const int4* __restrict__ AfH, const int4* __restrict__ AfL,
    const u64* __restrict__ gather,
    const __hip_bfloat16* __restrict__ Bh, const __hip_bfloat16* __restrict__ Bl,
    const float* __restrict__ bias, float* __restrict__ C) {
  __shared__ __align__(16) __hip_bfloat16 sAh[128 * 32];
  __shared__ __align__(16) __hip_bfloat16 sAl[128 * 32];
  __shared__ __align__(16) __hip_bfloat16 sBh[128 * 32];
  __shared__ __align__(16) __hip_bfloat16 sBl[128 * 32];
  const int t = threadIdx.x;
  const int w = t >> 6, l = t & 63;
  const int rowTile = blockIdx.y << 7;
  const int colTile = blockIdx.x << 7;
  const int wr = (w >> 1) << 6;
  const int wc = (w & 1) << 6;

  const int srow = t >> 2;
  const int sb = t & 3;
  const int skE = sb << 3;
  const int swz = (sb ^ ((srow >> 1) & 3)) << 3;
  const int wOff0 = (srow << 5) + swz;
  const int wOff1 = ((srow + 64) << 5) + swz;

  unsigned i0 = ((const unsigned*)gather)[2 * (rowTile + srow)];
  unsigned i1 = ((const unsigned*)gather)[2 * (rowTile + 64 + srow)];
  const int a0 = (int)((i0 >> 4) << 10) + (sb << 4) + (int)(i0 & 15);
  const int a1 = (int)((i1 >> 4) << 10) + (sb << 4) + (int)(i1 & 15);
  const size_t br0 = (size_t)(colTile + srow) * KD;
  const size_t br1 = (size_t)(colTile + 64 + srow) * KD;

  const int fr = l & 15;
  const int q = l >> 4;

  f32x4 acc[4][4];
#pragma unroll
  for (int i = 0; i < 4; ++i)
#pragma unroll
    for (int j = 0; j < 4; ++j) acc[i][j] = (f32x4){0.f, 0.f, 0.f, 0.f};

  for (int kk = 0; kk < KD; kk += 32) {
    const int kc64 = (kk >> 5) << 6;
    int4 vAh0 = AfH[a0 + kc64];
    int4 vAh1 = AfH[a1 + kc64];
    int4 vAl0 = AfL[a0 + kc64];
    int4 vAl1 = AfL[a1 + kc64];
    int4 vBh0 = *(const int4*)(Bh + br0 + kk + skE);
    int4 vBh1 = *(const int4*)(Bh + br1 + kk + skE);
    int4 vBl0 = *(const int4*)(Bl + br0 + kk + skE);
    int4 vBl1 = *(const int4*)(Bl + br1 + kk + skE);
    __syncthreads();
    *(int4*)(sAh + wOff0) = vAh0; *(int4*)(sAh + wOff1) = vAh1;
    *(int4*)(sAl + wOff0) = vAl0; *(int4*)(sAl + wOff1) = vAl1;
    *(int4*)(sBh + wOff0) = vBh0; *(int4*)(sBh + wOff1) = vBh1;
    *(int4*)(sBl + wOff0) = vBl0; *(int4*)(sBl + wOff1) = vBl1;
    __syncthreads();

    bf16x8 afh[4], afl[4], bfh[4], bfl[4];
#pragma unroll
    for (int mt = 0; mt < 4; ++mt) {
      const int rA = wr + (mt << 4) + fr;
      const int o = (rA << 5) + ((q ^ ((rA >> 1) & 3)) << 3);
      afh[mt] = *(const bf16x8*)(sAh + o);
      afl[mt] = *(const bf16x8*)(sAl + o);
    }
#pragma unroll
    for (int nt = 0; nt < 4; ++nt) {
      const int rB = wc + (nt << 4) + fr;
      const int o = (rB << 5) + ((q ^ ((rB >> 1) & 3)) << 3);
      bfh[nt] = *(const bf16x8*)(sBh + o);
      bfl[nt] = *(const bf16x8*)(sBl + o);
    }
#pragma unroll
    for (int mt = 0; mt < 4; ++mt)
#pragma unroll
      for (int nt = 0; nt < 4; ++nt) {
        acc[mt][nt] = __builtin_amdgcn_mfma_f32_16x16x32_bf16(afh[mt], bfh[nt], acc[mt][nt], 0, 0, 0);
        acc[mt][nt] = __builtin_amdgcn_mfma_f32_16x16x32_bf16(afh[mt], bfl[nt], acc[mt][nt], 0, 0, 0);
        acc[mt][nt] = __builtin_amdgcn_mfma_f32_16x16x32_bf16(afl[mt], bfh[nt], acc[mt][nt], 0, 0, 0);
      }
  }

  const int quad = l >> 4;
#pragma unroll
  for (int mt = 0; mt < 4; ++mt) {
#pragma unroll
    for (int reg = 0; reg < 4; ++reg) {
      const int row = rowTile + wr + (mt << 4) + (quad << 2) + reg;
#pragma unroll
      for (int nt = 0; nt < 4; ++nt) {
        const int col = colTile + wc + (nt << 4) + fr;
        C[(size_t)row * KD + col] = acc[mt][nt][reg] + bias[col];
      }
    }
  }
}

// ---- MLP GEMM 1-pass (hi*hi only): used for MLP2. fb feeds only
// out[...] * 0.1*gf (error ~5e-4 << 0.058 threshold), no argmin/tie-grid. ----
__global__ __launch_bounds__(256) void mlp1p(
    const int4* __restrict__ AfH,
    const u64* __restrict__ gather,
    const __hip_bfloat16* __restrict__ Bh,
    const float* __restrict__ bias, float* __restrict__ C) {
  __shared__ __align__(16) __hip_bfloat16 sAh[128 * 32];
  __shared__ __align__(16) __hip_bfloat16 sBh[128 * 32];
  const int t = threadIdx.x;
  const int w = t >> 6, l = t & 63;
  const int rowTile = blockIdx.y << 7;
  const int colTile = blockIdx.x << 7;
  const int wr = (w >> 1) << 6;
  const int wc = (w & 1) << 6;

  const int srow = t >> 2;
  const int sb = t & 3;
  const int skE = sb << 3;
  const int swz = (sb ^ ((srow >> 1) & 3)) << 3;
  const int wOff0 = (srow << 5) + swz;
  const int wOff1 = ((srow + 64) << 5) + swz;

  unsigned i0 = ((const unsigned*)gather)[2 * (rowTile + srow)];
  unsigned i1 = ((const unsigned*)gather)[2 * (rowTile + 64 + srow)];
  const int a0 = (int)((i0 >> 4) << 10) + (sb << 4) + (int)(i0 & 15);
  const int a1 = (int)((i1 >> 4) << 10) + (sb << 4) + (int)(i1 & 15);
  const size_t br0 = (size_t)(colTile + srow) * KD;
  const size_t br1 = (size_t)(colTile + 64 + srow) * KD;

  const int fr = l & 15;
  const int q = l >> 4;

  f32x4 acc[4][4];
#pragma unroll
  for (int i = 0; i < 4; ++i)
#pragma unroll
    for (int j = 0; j < 4; ++j) acc[i][j] = (f32x4){0.f, 0.f, 0.f, 0.f};

  for (int kk = 0; kk < KD; kk += 32) {
    const int kc64 = (kk >> 5) << 6;
    int4 vAh0 = AfH[a0 + kc64];
    int4 vAh1 = AfH[a1 + kc64];
    int4 vBh0 = *(const int4*)(Bh + br0 + kk + skE);
    int4 vBh1 = *(const int4*)(Bh + br1 + kk + skE);
    __syncthreads();
    *(int4*)(sAh + wOff0) = vAh0; *(int4*)(sAh + wOff1) = vAh1;
    *(int4*)(sBh + wOff0) = vBh0; *(int4*)(sBh + wOff1) = vBh1;
    __syncthreads();

    bf16x8 afh[4], bfh[4];
#pragma unroll
    for (int mt = 0; mt < 4; ++mt) {
      const int rA = wr + (mt << 4) + fr;
      const int o = (rA << 5) + ((q ^ ((rA >> 1) & 3)) << 3);
      afh[mt] = *(const bf16x8*)(sAh + o);
    }
#pragma unroll
    for (int nt = 0; nt < 4; ++nt) {
      const int rB = wc + (nt << 4) + fr;
      const int o = (rB << 5) + ((q ^ ((rB >> 1) & 3)) << 3);
      bfh[nt] = *(const bf16x8*)(sBh + o);
    }
#pragma unroll
    for (int mt = 0; mt < 4; ++mt)
#pragma unroll
      for (int nt = 0; nt < 4; ++nt)
        acc[mt][nt] = __builtin_amdgcn_mfma_f32_16x16x32_bf16(afh[mt], bfh[nt], acc[mt][nt], 0, 0, 0);
  }

  const int quad = l >> 4;
#pragma unroll
  for (int mt = 0; mt < 4; ++mt) {
#pragma unroll
    for (int reg = 0; reg < 4; ++reg) {
      const int row = rowTile + wr + (mt << 4) + (quad << 2) + reg;
#pragma unroll
      for (int nt = 0; nt < 4; ++nt) {
        const int col = colTile + wc + (nt << 4) + fr;
        C[(size_t)row * KD + col] = acc[mt][nt][reg] + bias[col];
      }
    }
  }
}

// ---- LN + leaky -> influence(bf16); residual hi(bf16) + f32 + norms ----
__global__ __launch_bounds__(256) void ln_residual(
    const float* __restrict__ h, const float* __restrict__ g, const float* __restrict__ be,
    const float* __restrict__ z, const float* __restrict__ gRaw,
    __hip_bfloat16* __restrict__ infl, float* __restrict__ rn,
    __hip_bfloat16* __restrict__ rH, float* __restrict__ resF) {
  __shared__ float sred[4];
  const int row = blockIdx.x, t = threadIdx.x;
  const size_t base = (size_t)row * KD;
  float h0 = h[base + t], h1 = h[base + t + 256];
  float m = block_sum(h0 + h1, sred) * (1.0f / 512.0f);
  float d0 = h0 - m, d1 = h1 - m;
  float var = block_sum(d0 * d0 + d1 * d1, sred) * (1.0f / 512.0f);
  float sq = sqrtf(var + 1e-5f);
  float gc = sigmoidf_(gRaw[0]);
  float v0 = d0 / sq * g[t] + be[t];
  float v1 = d1 / sq * g[t + 256] + be[t + 256];
  v0 = v0 > 0.0f ? v0 : 0.1f * v0;
  v1 = v1 > 0.0f ? v1 : 0.1f * v1;
  infl[base + t] = __float2bfloat16(v0);
  infl[base + t + 256] = __float2bfloat16(v1);
  float zf0 = z[(size_t)row * 1024 + 512 + t];
  float zf1 = z[(size_t)row * 1024 + 512 + t + 256];
  float r0 = zf0 - gc * v0, r1 = zf1 - gc * v1;
  rH[base + t] = __float2bfloat16(r0);
  rH[base + t + 256] = __float2bfloat16(r1);
  resF[base + t] = r0;
  resF[base + t + 256] = r1;
  float rs = block_sum(r0 * r0 + r1 * r1, sred);
  if (t == 0) rn[row] = rs;
}

// ---- LN+leaky on h2, gather q_c/q_f, outputs + loss; last block writes
// the loss scalar (device-scope atomic counter + fence; atomicAdd(lossp,0)
// read avoids stale L1). Counter zeroed by prep each iteration. ----
__global__ __launch_bounds__(256) void finalize(
    const float* __restrict__ h, const float* __restrict__ g, const float* __restrict__ be,
    const __hip_bfloat16* __restrict__ infl,
    const u64* __restrict__ amc, const u64* __restrict__ amf,
    const float* __restrict__ z, const float* __restrict__ ce, const float* __restrict__ fe,
    const float* __restrict__ gcRaw, const float* __restrict__ gfRaw,
    float* __restrict__ out, float* __restrict__ lossp, unsigned* __restrict__ donecnt) {
  __shared__ float sred[4];
  const int row = blockIdx.x, t = threadIdx.x;
  const size_t base = (size_t)row * KD;
  float h0 = h[base + t], h1 = h[base + t + 256];
  float m = block_sum(h0 + h1, sred) * (1.0f / 512.0f);
  float d0 = h0 - m, d1 = h1 - m;
  float var = block_sum(d0 * d0 + d1 * d1, sred) * (1.0f / 512.0f);
  float sq = sqrtf(var + 1e-5f);
  float fb0 = d0 / sq * g[t] + be[t];
  float fb1 = d1 / sq * g[t + 256] + be[t + 256];
  fb0 = fb0 > 0.0f ? fb0 : 0.1f * fb0;
  fb1 = fb1 > 0.0f ? fb1 : 0.1f * fb1;
  float gc = sigmoidf_(gcRaw[0]);
  float gf = sigmoidf_(gfRaw[0]);
  unsigned ic = (unsigned)(amc[row] & 0xffffffffULL);
  unsigned ifx = (unsigned)(amf[row] & 0xffffffffULL);
  float loc = 0.0f;
#pragma unroll
  for (int j = 0; j < 2; ++j) {
    int c = t + j * 256;
    float fb = j ? fb1 : fb0;
    float qc = ce[(size_t)ic * KD + c];
    float qf = fe[(size_t)ifx * KD + c];
    float zc = z[(size_t)row * 1024 + c];
    float zf = z[(size_t)row * 1024 + 512 + c];
    float fl = __bfloat162float(infl[base + c]);
    out[(size_t)row * 1024 + c] = qc + 0.1f * gf * fb;
    out[(size_t)row * 1024 + 512 + c] = qf + gc * fl;
    float dc = qc - zc;
    float res = zf - gc * fl;
    float df = qf - res;
    loc += dc * dc + df * df;
  }
  float ls = block_sum(loc, sred);
  if (t == 0) {
    atomicAdd(lossp, ls);
    __threadfence();                             // release lossp before counter
    unsigned done = atomicAdd(donecnt, 1u);
    if (done == 8191u) {
      float total = atomicAdd(lossp, 0.0f);      // device-coherent read
      out[(size_t)8192 * 1024] = 1.25f * total / (8192.0f * 512.0f);
    }
  }
}

extern "C" void kernel_launch(void* const* d_in, const int* in_sizes, int n_in,
                              void* d_out, int out_size, void* d_ws, size_t ws_size,
                              hipStream_t stream) {
  const float* z      = (const float*)d_in[0];
  const float* ce     = (const float*)d_in[1];
  const float* fe     = (const float*)d_in[2];
  const float* w_c2f  = (const float*)d_in[3];
  const float* b_c2f  = (const float*)d_in[4];
  const float* g_c2f  = (const float*)d_in[5];
  const float* be_c2f = (const float*)d_in[6];
  const float* w_f2c  = (const float*)d_in[7];
  const float* b_f2c  = (const float*)d_in[8];
  const float* g_f2c  = (const float*)d_in[9];
  const float* be_f2c = (const float*)d_in[10];
  const float* gcRaw  = (const float*)d_in[11];
  const float* gfRaw  = (const float*)d_in[12];
  float* out = (float*)d_out;
  char* ws = (char*)d_ws;

  float* cn = (float*)(ws + OFF_CN);
  float* fn = (float*)(ws + OFF_FN);
  float* zn = (float*)(ws + OFF_ZN);
  float* rn = (float*)(ws + OFF_RN);
  float* lossp = (float*)(ws + OFF_LOSS);
  unsigned* donecnt = (unsigned*)(ws + OFF_LOSS + 4);
  u64* amc = (u64*)(ws + OFF_AMC);
  u64* amf = (u64*)(ws + OFF_AMF);
  __hip_bfloat16* ceH = (__hip_bfloat16*)(ws + OFF_CEH);
  __hip_bfloat16* ceL = (__hip_bfloat16*)(ws + OFF_CEL);
  __hip_bfloat16* feH = (__hip_bfloat16*)(ws + OFF_FEH);
  __hip_bfloat16* feL = (__hip_bfloat16*)(ws + OFF_FEL);
  __hip_bfloat16* zcH = (__hip_bfloat16*)(ws + OFF_ZCH);
  __hip_bfloat16* rH  = (__hip_bfloat16*)(ws + OFF_RH);
  __hip_bfloat16* w1H = (__hip_bfloat16*)(ws + OFF_W1H);
  __hip_bfloat16* w1L = (__hip_bfloat16*)(ws + OFF_W1L);
  __hip_bfloat16* w2H = (__hip_bfloat16*)(ws + OFF_W2H);
  __hip_bfloat16* w2L = (__hip_bfloat16*)(ws + OFF_W2L);
  float* h = (float*)(ws + OFF_H);
  __hip_bfloat16* infl = (__hip_bfloat16*)(ws + OFF_INFL);
  u64* bkeys = (u64*)(ws + OFF_H);        // reused during VQ stages
  float* resF = (float*)(ws + OFF_ZCH);   // 16.78 MB, reuses zcH+zcL after coarse VQ

  // norms + splits (codebooks -> frag layout); zero loss + done-counter
  prep<<<21504, 256, 0, stream>>>(ce, fe, z, w_c2f, w_f2c, cn, fn, zn,
                                  ceH, ceL, feH, feL, zcH,
                                  w1H, w1L, w2H, w2L, lossp);

  // coarse VQ approx: 4096 codes (16 y-tiles of 256) x 8192 queries
  vq10<<<dim3(64, 16), 256, 0, stream>>>((const int4*)ceH, zcH, cn, bkeys);

  // coarse rescue: exact f32 rescore (reference-matching arithmetic) -> amc
  rescue<<<2048, 256, 0, stream>>>(bkeys, 48, z, 1024, ce, zn, cn, 0.00321f, amc);

  // MLP1 (3-pass): h = gather(ce, amc) @ w_c2f^T + b
  mlp6<<<dim3(4, 64), 256, 0, stream>>>((const int4*)ceH, (const int4*)ceL, amc,
                                        w1H, w1L, b_c2f, h);

  // LN + leaky -> influence (bf16); residual hi + f32 + norms
  ln_residual<<<8192, 256, 0, stream>>>(h, g_c2f, be_c2f, z, gcRaw, infl, rn, rH, resF);

  // fine VQ approx: 8192 codes (32 y-tiles of 256) x 8192 queries
  vq10<<<dim3(64, 32), 256, 0, stream>>>((const int4*)feH, rH, fn, bkeys);

  // fine rescue -> amf
  rescue<<<2048, 256, 0, stream>>>(bkeys, 96, resF, 512, fe, rn, fn, 0.00233f, amf);

  // MLP2 (1-pass): h = gather(fe, amf) @ w_f2c^T + b
  mlp1p<<<dim3(4, 64), 256, 0, stream>>>((const int4*)feH, amf, w2H, b_f2c, h);

  // outputs + loss (loss scalar written by last block — loss_write fused)
  finalize<<<8192, 256, 0, stream>>>(h, g_f2c, be_f2c, infl, amc, amf, z, ce, fe,
                                     gcRaw, gfRaw, out, lossp, donecnt);
}

// Round 11
// 530.221 us; speedup vs baseline: 1.2895x; 1.2895x over previous
//
#include <hip/hip_runtime.h>
#include <hip/hip_bf16.h>
#include <cstdint>
#include <cstddef>

#define KD 512

// ---- workspace byte offsets ----
#define OFF_CN   0u           // 4096 f32 coarse codebook norms
#define OFF_FN   16384u       // 8192 f32 fine codebook norms
#define OFF_ZN   49152u       // 8192 f32 z-coarse row norms
#define OFF_RN   81920u       // 8192 f32 residual row norms
#define OFF_LOSS 114688u      // 1 f32 loss accumulator
#define OFF_AMC  114944u      // 8192 u64 coarse argmin keys
#define OFF_AMF  180480u      // 8192 u64 fine argmin keys
#define OFF_CEH  246016u      // 4096x512 bf16 coarse emb hi (FRAG layout)
#define OFF_CEL  4440320u     // 4096x512 bf16 coarse emb lo (FRAG layout)
#define OFF_FEH  8634624u     // 8192x512 bf16 fine emb hi (FRAG layout)
#define OFF_FEL  17023232u    // 8192x512 bf16 fine emb lo (FRAG layout)
#define OFF_ZCH  25411840u    // 8192x512 bf16 z-coarse hi (row-major); REUSED as f32 residual after coarse VQ
#define OFF_ZCL  33800448u
#define OFF_RH   42189056u    // 8192x512 bf16 residual hi (row-major)
#define OFF_RL   50577664u    // (unused)
#define OFF_W1H  58966272u    // 512x512 bf16 w_c2f hi (row-major)
#define OFF_W1L  59490560u
#define OFF_W2H  60014848u
#define OFF_W2L  60539136u
#define OFF_H    61063424u    // 8192x512 f32; REUSED as block-keys during VQ stages
#define OFF_INFL 77840640u    // 8192x512 bf16
// total = 86,229,248 bytes

// frag layout: 16B chunk index = ((row>>4)*16 + (k>>5))*64 + lane,
// lane = (row&15) | (((k>>3)&3)<<4); chunk holds elems k..k+7 of row.

typedef __attribute__((ext_vector_type(8))) short bf16x8;
typedef __attribute__((ext_vector_type(4))) float f32x4;
typedef unsigned long long u64;

__device__ __forceinline__ bf16x8 as_bf16x8(int4 v) {
  union { int4 i; bf16x8 b; } u; u.i = v; return u.b;
}

__device__ __forceinline__ void gl_lds16(const void* g, void* l) {
  __builtin_amdgcn_global_load_lds(
      (const __attribute__((address_space(1))) void*)g,
      (__attribute__((address_space(3))) void*)l, 16, 0, 0);
}

__device__ __forceinline__ float block_sum(float v, float* sred) {
#pragma unroll
  for (int off = 32; off > 0; off >>= 1) v += __shfl_down(v, off, 64);
  if ((threadIdx.x & 63) == 0) sred[threadIdx.x >> 6] = v;
  __syncthreads();
  float r = sred[0] + sred[1] + sred[2] + sred[3];
  __syncthreads();
  return r;
}

__device__ __forceinline__ float sigmoidf_(float x) { return 1.0f / (1.0f + expf(-x)); }

__device__ __forceinline__ void split_bf16(float v, __hip_bfloat16* hi, __hip_bfloat16* lo) {
  __hip_bfloat16 h = __float2bfloat16(v);
  *hi = h;
  *lo = __float2bfloat16(v - __bfloat162float(h));
}

__device__ __forceinline__ unsigned enc_sortable(float f) {
  unsigned u = __float_as_uint(f);
  return (u & 0x80000000u) ? ~u : (u | 0x80000000u);
}
__device__ __forceinline__ float dec_sortable(unsigned ub) {
  unsigned o = (ub & 0x80000000u) ? (ub & 0x7fffffffu) : ~ub;
  return __uint_as_float(o);
}
__device__ __forceinline__ u64 umin64(u64 a, u64 b) { return a < b ? a : b; }
__device__ __forceinline__ u64 umax64(u64 a, u64 b) { return a > b ? a : b; }

// merge two sorted triples (a1<=a2<=a3, b1<=b2<=b3) -> top-3 of union in a
__device__ __forceinline__ void merge3(u64& a1, u64& a2, u64& a3, u64 b1, u64 b2, u64 b3) {
  u64 p = umax64(a1, b1);
  u64 q = umin64(a2, b2);
  u64 r = umax64(a2, b2);
  u64 s = umin64(a3, b3);
  u64 m1 = umin64(a1, b1);
  u64 m2 = umin64(p, q);
  u64 m3 = umin64(umin64(umax64(p, q), r), s);
  a1 = m1; a2 = m2; a3 = m3;
}

// ---- prep: norms + splits. Codebooks -> FRAG layout (hi+lo); zc -> row-major hi only;
// weights -> row-major hi+lo. Norm reduction order UNCHANGED (tie-grid — R1).
// Frag-pack reads the row from LDS (staged during the norm phase) instead of
// re-reading global — bit-identical f32s, kills the 2nd global read (R10 fix,
// kept). NO device fences anywhere (R10 threadfence = L2-flush storm, -154us). ----
__global__ __launch_bounds__(256) void prep(
    const float* __restrict__ ce, const float* __restrict__ fe, const float* __restrict__ z,
    const float* __restrict__ w1, const float* __restrict__ w2,
    float* __restrict__ cn, float* __restrict__ fn, float* __restrict__ zn,
    __hip_bfloat16* __restrict__ ceH, __hip_bfloat16* __restrict__ ceL,
    __hip_bfloat16* __restrict__ feH, __hip_bfloat16* __restrict__ feL,
    __hip_bfloat16* __restrict__ zcH,
    __hip_bfloat16* __restrict__ w1H, __hip_bfloat16* __restrict__ w1L,
    __hip_bfloat16* __restrict__ w2H, __hip_bfloat16* __restrict__ w2L,
    float* __restrict__ lossp) {
  __shared__ float sred[4];
  __shared__ float srow_[512];
  const int b = blockIdx.x, t = threadIdx.x;
  const float* src;
  float* nd = nullptr;
  __hip_bfloat16 *dh = nullptr, *dl = nullptr;
  int fragMode = 0, hiOnly = 0;
  size_t row;
  if (b < 4096) {
    row = b; src = ce + row * KD; nd = cn + row; dh = ceH; dl = ceL; fragMode = 1;
  } else if (b < 12288) {
    row = b - 4096; src = fe + row * KD; nd = fn + row; dh = feH; dl = feL; fragMode = 1;
  } else if (b < 20480) {
    row = b - 12288; src = z + row * 1024; nd = zn + row; dh = zcH; hiOnly = 1;
  } else if (b < 20992) {
    row = b - 20480; src = w1 + row * KD; dh = w1H; dl = w1L;
  } else {
    row = b - 20992; src = w2 + row * KD; dh = w2H; dl = w2L;
  }
  float acc = 0.0f;
  if (fragMode) {
    float v0 = src[t], v1 = src[t + 256];
    srow_[t] = v0;          // stage for the pack phase (visible after block_sum's syncs)
    srow_[t + 256] = v1;
    acc = v0 * v0 + v1 * v1;
  } else {
#pragma unroll
    for (int j = 0; j < 2; ++j) {
      int c = t + j * 256;
      float v = src[c];
      acc += v * v;
      __hip_bfloat16 h, l;
      split_bf16(v, &h, &l);
      dh[row * KD + c] = h;
      if (!hiOnly) dl[row * KD + c] = l;
    }
  }
  if (nd) {
    float s = block_sum(acc, sred);
    if (t == 0) nd[0] = s;
  } else {
    __syncthreads();  // keep barrier count uniform (block_sum has syncs)
    __syncthreads();
  }
  if (fragMode && t < 64) {
    // thread t: elems [8t, 8t+8) from LDS -> one 16B chunk each for hi/lo
    union { int4 i; __hip_bfloat16 s[8]; } ph, pl;
#pragma unroll
    for (int j = 0; j < 8; ++j) {
      float v = srow_[8 * t + j];
      split_bf16(v, &ph.s[j], &pl.s[j]);
    }
    const int chunkIdx = (int)(((row >> 4) * 16 + (t >> 2)) * 64 +
                               ((size_t)((t & 3) << 4) | (row & 15)));
    ((int4*)dh)[chunkIdx] = ph.i;
    ((int4*)dl)[chunkIdx] = pl.i;
  }
  if (b == 20480 && t == 0) lossp[0] = 0.0f;
}

// ---- VQ v10 (R6/R8, proven best @132us fine): 256 codes x 128 queries per block.
// A+B staged via global_load_lds into 3-deep LDS rings, 2 chunks ahead; one
// raw s_barrier per iter; counted vmcnt(6) (one chunk = 6 DMAs/wave), drained
// only at i=15. Hazards audited R5/R6. NATIVE mapping keeps B L2-resident.
__global__ __launch_bounds__(256, 2) void vq10(
    const int4* __restrict__ AfH,
    const __hip_bfloat16* __restrict__ Bh,
    const float* __restrict__ cn,
    u64* __restrict__ bkeys) {   // [8192][gridDim.y][3]
  __shared__ __align__(16) int4 sA[3][1024];                // 16KB/slot (256 rows x 32k)
  __shared__ __align__(16) __hip_bfloat16 sB[3][128 * 32];  // 8KB/slot
  const int t = threadIdx.x;
  const int w = t >> 6, l = t & 63;

  const int bx = blockIdx.x;
  const int by = blockIdx.y;
  const int rowTile = by << 8;  // 256 codes
  const int colTile = bx << 7;  // 128 queries
  const int NB = gridDim.y;

  // B staging (geometry proven v7-v10): wave w stages query rows [32w,32w+32);
  // linear LDS dest, pre-swizzled global source chunk.
  const int rl = l >> 2;
  const int sbp = (l & 3) ^ ((l >> 3) & 3);
  const size_t gOff0 = (size_t)(colTile + (w << 5) + rl) * KD + (sbp << 3);
  const size_t gOff1 = gOff0 + (size_t)16 * KD;
  const int lOffB0 = (w << 5) << 5;     // elements
  const int lOffB1 = lOffB0 + (16 << 5);

  // A staging: wave w stages row-groups 4w..4w+3 (of 16 per block).
  const int rtg = rowTile >> 4;
  const int aS0 = ((rtg + 4 * w + 0) << 10) + l;
  const int aS1 = ((rtg + 4 * w + 1) << 10) + l;
  const int aS2 = ((rtg + 4 * w + 2) << 10) + l;
  const int aS3 = ((rtg + 4 * w + 3) << 10) + l;

  const int fr = l & 15;
  const int q = l >> 4;

  // wave w computes codes [64w, 64w+64) x all 128 queries: acc[mt 0..3][nt 0..7]
  f32x4 acc[4][8];
#pragma unroll
  for (int i = 0; i < 4; ++i)
#pragma unroll
    for (int j = 0; j < 8; ++j) acc[i][j] = (f32x4){0.f, 0.f, 0.f, 0.f};

#define STAGE(ck) do {                                                   \
    const int sl_ = (ck) % 3;                                            \
    gl_lds16(AfH + aS0 + ((ck) << 6), &sA[sl_][(4 * w + 0) << 6]);       \
    gl_lds16(AfH + aS1 + ((ck) << 6), &sA[sl_][(4 * w + 1) << 6]);       \
    gl_lds16(AfH + aS2 + ((ck) << 6), &sA[sl_][(4 * w + 2) << 6]);       \
    gl_lds16(AfH + aS3 + ((ck) << 6), &sA[sl_][(4 * w + 3) << 6]);       \
    gl_lds16(Bh + gOff0 + ((size_t)(ck) << 5), &sB[sl_][lOffB0]);        \
    gl_lds16(Bh + gOff1 + ((size_t)(ck) << 5), &sB[sl_][lOffB1]);        \
  } while (0)

  // prologue: stage chunks 0,1 -> slots 0,1; 12 DMAs in flight per wave.
  STAGE(0);
  STAGE(1);
  __builtin_amdgcn_sched_barrier(0);

#pragma unroll
  for (int i = 0; i < 16; ++i) {
    // chunk-i DMAs landed (oldest 6 of <=12 outstanding) + prev iter reads done
    if (i < 15) asm volatile("s_waitcnt vmcnt(6) lgkmcnt(0)" ::: "memory");
    else        asm volatile("s_waitcnt vmcnt(0) lgkmcnt(0)" ::: "memory");
    __builtin_amdgcn_s_barrier();
    __builtin_amdgcn_sched_barrier(0);
    if (i + 2 < 16) STAGE(i + 2);   // overwrites slot (i-1)%3: safe
    __builtin_amdgcn_sched_barrier(0);

    const int cb = i % 3;
    bf16x8 afh[4], bfh[8];
#pragma unroll
    for (int mt = 0; mt < 4; ++mt)
      afh[mt] = as_bf16x8(sA[cb][((4 * w) + mt) * 64 + l]);
#pragma unroll
    for (int nt = 0; nt < 8; ++nt) {
      const int rB = (nt << 4) + fr;
      const int o = (rB << 5) + ((q ^ ((rB >> 1) & 3)) << 3);
      bfh[nt] = *(const bf16x8*)(sB[cb] + o);
    }
    __builtin_amdgcn_s_setprio(1);
#pragma unroll
    for (int mt = 0; mt < 4; ++mt)
#pragma unroll
      for (int nt = 0; nt < 8; ++nt)
        acc[mt][nt] = __builtin_amdgcn_mfma_f32_16x16x32_bf16(afh[mt], bfh[nt], acc[mt][nt], 0, 0, 0);
    __builtin_amdgcn_s_setprio(0);
  }
#undef STAGE

  // epilogue: per query, top-3 over this block's 256 codes.
  u64 tk1[8], tk2[8], tk3[8];
#pragma unroll
  for (int nt = 0; nt < 8; ++nt) {
    u64 t1 = ~0ULL, t2 = ~0ULL, t3 = ~0ULL;
#pragma unroll
    for (int mt = 0; mt < 4; ++mt) {
#pragma unroll
      for (int reg = 0; reg < 4; ++reg) {
        const int code = rowTile + (w << 6) + (mt << 4) + (q << 2) + reg;
        float d = cn[code] - 2.0f * acc[mt][nt][reg];
        u64 key = ((u64)enc_sortable(d) << 32) | (u64)(unsigned)code;
        if (key < t1) { t3 = t2; t2 = t1; t1 = key; }
        else if (key < t2) { t3 = t2; t2 = key; }
        else if (key < t3) { t3 = key; }
      }
    }
    // merge across the 4 q-lanes holding the same query (fr)
#pragma unroll
    for (int off = 16; off <= 32; off <<= 1) {
      u64 b1 = __shfl_xor(t1, off, 64);
      u64 b2 = __shfl_xor(t2, off, 64);
      u64 b3 = __shfl_xor(t3, off, 64);
      merge3(t1, t2, t3, b1, b2, b3);
    }
    tk1[nt] = t1; tk2[nt] = t2; tk3[nt] = t3;
  }

  // cross-wave merge: all 4 waves cover the same 128 queries (codes stacked).
  __syncthreads();  // all LDS reads/DMAs done; reuse sA as key buffer (12KB)
  u64* sk = (u64*)sA;
  if (w > 0 && l < 16) {
#pragma unroll
    for (int nt = 0; nt < 8; ++nt) {
      const int o = (((w << 3) + nt) * 16 + fr) * 3;
      sk[o] = tk1[nt]; sk[o + 1] = tk2[nt]; sk[o + 2] = tk3[nt];
    }
  }
  __syncthreads();
  if (w == 0 && l < 16) {
#pragma unroll
    for (int nt = 0; nt < 8; ++nt) {
      u64 t1 = tk1[nt], t2 = tk2[nt], t3 = tk3[nt];
#pragma unroll
      for (int wv = 1; wv < 4; ++wv) {
        const int o = (((wv << 3) + nt) * 16 + fr) * 3;
        merge3(t1, t2, t3, sk[o], sk[o + 1], sk[o + 2]);
      }
      const int query = colTile + (nt << 4) + fr;
      const size_t bo = ((size_t)query * NB + by) * 3;
      bkeys[bo] = t1; bkeys[bo + 1] = t2; bkeys[bo + 2] = t3;
    }
  }
}

// ---- rescue: per query, gather block top-3 keys, exact-f32 rescore all
// candidates within delta of the approximate min; write final argmin key.
// Exact d replicates the reference's arithmetic: (xn + cn) - 2*dot at
// magnitude ~512 (see R1 post-mortem — tie-grid must match). ----
__global__ __launch_bounds__(256) void rescue(
    const u64* __restrict__ bkeys, int NB3,
    const float* __restrict__ Q, int qStride,
    const float* __restrict__ Cb,
    const float* __restrict__ qn, const float* __restrict__ cnorm,
    float dscale, u64* __restrict__ am) {
  const int wv = threadIdx.x >> 6, l = threadIdx.x & 63;
  const int qi = (blockIdx.x << 2) + wv;
  const u64* kq = bkeys + (size_t)qi * NB3;
  u64 kk[3];
#pragma unroll
  for (int j = 0; j < 3; ++j) {
    const int idx = l + (j << 6);
    kk[j] = (idx < NB3) ? kq[idx] : ~0ULL;
  }
  u64 kmin = umin64(kk[0], umin64(kk[1], kk[2]));
#pragma unroll
  for (int off = 32; off > 0; off >>= 1) kmin = umin64(kmin, __shfl_xor(kmin, off, 64));
  const float xnv = qn[qi];
  const float dmin = dec_sortable((unsigned)(kmin >> 32));
  const float thr = dmin + dscale * sqrtf(xnv) + 0.01f;
  const u64 thrKey = ((u64)enc_sortable(thr) << 32) | 0xffffffffULL;

  const float* qrow = Q + (size_t)qi * qStride;
  const float4 qa = *(const float4*)(qrow + (l << 3));
  const float4 qb = *(const float4*)(qrow + (l << 3) + 4);
  float bestD = 3.4e38f;
  int bestC = 0x7fffffff;
#pragma unroll
  for (int j = 0; j < 3; ++j) {
    bool pend = kk[j] <= thrKey;
    u64 mask;
    while ((mask = __ballot(pend)) != 0ULL) {
      const int src = __ffsll((unsigned long long)mask) - 1;
      const u64 key = __shfl(kk[j], src, 64);
      if (l == src) pend = false;
      const int code = (int)(unsigned)(key & 0xffffffffULL);
      const float* crow = Cb + (size_t)code * KD;
      const float4 ca = *(const float4*)(crow + (l << 3));
      const float4 cb = *(const float4*)(crow + (l << 3) + 4);
      float dt = qa.x * ca.x + qa.y * ca.y + qa.z * ca.z + qa.w * ca.w +
                 qb.x * cb.x + qb.y * cb.y + qb.z * cb.z + qb.w * cb.w;
#pragma unroll
      for (int off = 32; off > 0; off >>= 1) dt += __shfl_xor(dt, off, 64);
      const float d = (xnv + cnorm[code]) - 2.0f * dt;
      if (d < bestD || (d == bestD && code < bestC)) { bestD = d; bestC = code; }
    }
  }
  if (l == 0) am[qi] = ((u64)enc_sortable(bestD) << 32) | (unsigned)bestC;
}

// ---- MLP GEMM (3-pass hi/lo): A = gathered codebook rows (frag), B = weights.
// MLP1 only — output feeds the fine-VQ query (residual): bf16x3 required. ----
__global__ __launch_bounds__(256) void mlp6(
    const int4* __restrict__ AfH, const int4* __restrict__ AfL,
    const u64* __restrict__ gather,
    const __hip_bfloat16* __restrict__ Bh, const __hip_bfloat16* __restrict__ Bl,
    const float* __restrict__ bias, float* __restrict__ C) {
  __shared__ __align__(16) __hip_bfloat16 sAh[128 * 32];
  __shared__ __align__(16) __hip_bfloat16 sAl[128 * 32];
  __shared__ __align__(16) __hip_bfloat16 sBh[128 * 32];
  __shared__ __align__(16) __hip_bfloat16 sBl[128 * 32];
  const int t = threadIdx.x;
  const int w = t >> 6, l = t & 63;
  const int rowTile = blockIdx.y << 7;
  const int colTile = blockIdx.x << 7;
  const int wr = (w >> 1) << 6;
  const int wc = (w & 1) << 6;

  const int srow = t >> 2;
  const int sb = t & 3;
  const int skE = sb << 3;
  const int swz = (sb ^ ((srow >> 1) & 3)) << 3;
  const int wOff0 = (srow << 5) + swz;
  const int wOff1 = ((srow + 64) << 5) + swz;

  unsigned i0 = ((const unsigned*)gather)[2 * (rowTile + srow)];
  unsigned i1 = ((const unsigned*)gather)[2 * (rowTile + 64 + srow)];
  const int a0 = (int)((i0 >> 4) << 10) + (sb << 4) + (int)(i0 & 15);
  const int a1 = (int)((i1 >> 4) << 10) + (sb << 4) + (int)(i1 & 15);
  const size_t br0 = (size_t)(colTile + srow) * KD;
  const size_t br1 = (size_t)(colTile + 64 + srow) * KD;

  const int fr = l & 15;
  const int q = l >> 4;

  f32x4 acc[4][4];
#pragma unroll
  for (int i = 0; i < 4; ++i)
#pragma unroll
    for (int j = 0; j < 4; ++j) acc[i][j] = (f32x4){0.f, 0.f, 0.f, 0.f};

  for (int kk = 0; kk < KD; kk += 32) {
    const int kc64 = (kk >> 5) << 6;
    int4 vAh0 = AfH[a0 + kc64];
    int4 vAh1 = AfH[a1 + kc64];
    int4 vAl0 = AfL[a0 + kc64];
    int4 vAl1 = AfL[a1 + kc64];
    int4 vBh0 = *(const int4*)(Bh + br0 + kk + skE);
    int4 vBh1 = *(const int4*)(Bh + br1 + kk + skE);
    int4 vBl0 = *(const int4*)(Bl + br0 + kk + skE);
    int4 vBl1 = *(const int4*)(Bl + br1 + kk + skE);
    __syncthreads();
    *(int4*)(sAh + wOff0) = vAh0; *(int4*)(sAh + wOff1) = vAh1;
    *(int4*)(sAl + wOff0) = vAl0; *(int4*)(sAl + wOff1) = vAl1;
    *(int4*)(sBh + wOff0) = vBh0; *(int4*)(sBh + wOff1) = vBh1;
    *(int4*)(sBl + wOff0) = vBl0; *(int4*)(sBl + wOff1) = vBl1;
    __syncthreads();

    bf16x8 afh[4], afl[4], bfh[4], bfl[4];
#pragma unroll
    for (int mt = 0; mt < 4; ++mt) {
      const int rA = wr + (mt << 4) + fr;
      const int o = (rA << 5) + ((q ^ ((rA >> 1) & 3)) << 3);
      afh[mt] = *(const bf16x8*)(sAh + o);
      afl[mt] = *(const bf16x8*)(sAl + o);
    }
#pragma unroll
    for (int nt = 0; nt < 4; ++nt) {
      const int rB = wc + (nt << 4) + fr;
      const int o = (rB << 5) + ((q ^ ((rB >> 1) & 3)) << 3);
      bfh[nt] = *(const bf16x8*)(sBh + o);
      bfl[nt] = *(const bf16x8*)(sBl + o);
    }
#pragma unroll
    for (int mt = 0; mt < 4; ++mt)
#pragma unroll
      for (int nt = 0; nt < 4; ++nt) {
        acc[mt][nt] = __builtin_amdgcn_mfma_f32_16x16x32_bf16(afh[mt], bfh[nt], acc[mt][nt], 0, 0, 0);
        acc[mt][nt] = __builtin_amdgcn_mfma_f32_16x16x32_bf16(afh[mt], bfl[nt], acc[mt][nt], 0, 0, 0);
        acc[mt][nt] = __builtin_amdgcn_mfma_f32_16x16x32_bf16(afl[mt], bfh[nt], acc[mt][nt], 0, 0, 0);
      }
  }

  const int quad = l >> 4;
#pragma unroll
  for (int mt = 0; mt < 4; ++mt) {
#pragma unroll
    for (int reg = 0; reg < 4; ++reg) {
      const int row = rowTile + wr + (mt << 4) + (quad << 2) + reg;
#pragma unroll
      for (int nt = 0; nt < 4; ++nt) {
        const int col = colTile + wc + (nt << 4) + fr;
        C[(size_t)row * KD + col] = acc[mt][nt][reg] + bias[col];
      }
    }
  }
}

// ---- MLP GEMM 1-pass (hi*hi only): used for MLP2. fb feeds only
// out[...] * 0.1*gf (error ~5e-4 << 0.058 threshold), no argmin/tie-grid. ----
__global__ __launch_bounds__(256) void mlp1p(
    const int4* __restrict__ AfH,
    const u64* __restrict__ gather,
    const __hip_bfloat16* __restrict__ Bh,
    const float* __restrict__ bias, float* __restrict__ C) {
  __shared__ __align__(16) __hip_bfloat16 sAh[128 * 32];
  __shared__ __align__(16) __hip_bfloat16 sBh[128 * 32];
  const int t = threadIdx.x;
  const int w = t >> 6, l = t & 63;
  const int rowTile = blockIdx.y << 7;
  const int colTile = blockIdx.x << 7;
  const int wr = (w >> 1) << 6;
  const int wc = (w & 1) << 6;

  const int srow = t >> 2;
  const int sb = t & 3;
  const int skE = sb << 3;
  const int swz = (sb ^ ((srow >> 1) & 3)) << 3;
  const int wOff0 = (srow << 5) + swz;
  const int wOff1 = ((srow + 64) << 5) + swz;

  unsigned i0 = ((const unsigned*)gather)[2 * (rowTile + srow)];
  unsigned i1 = ((const unsigned*)gather)[2 * (rowTile + 64 + srow)];
  const int a0 = (int)((i0 >> 4) << 10) + (sb << 4) + (int)(i0 & 15);
  const int a1 = (int)((i1 >> 4) << 10) + (sb << 4) + (int)(i1 & 15);
  const size_t br0 = (size_t)(colTile + srow) * KD;
  const size_t br1 = (size_t)(colTile + 64 + srow) * KD;

  const int fr = l & 15;
  const int q = l >> 4;

  f32x4 acc[4][4];
#pragma unroll
  for (int i = 0; i < 4; ++i)
#pragma unroll
    for (int j = 0; j < 4; ++j) acc[i][j] = (f32x4){0.f, 0.f, 0.f, 0.f};

  for (int kk = 0; kk < KD; kk += 32) {
    const int kc64 = (kk >> 5) << 6;
    int4 vAh0 = AfH[a0 + kc64];
    int4 vAh1 = AfH[a1 + kc64];
    int4 vBh0 = *(const int4*)(Bh + br0 + kk + skE);
    int4 vBh1 = *(const int4*)(Bh + br1 + kk + skE);
    __syncthreads();
    *(int4*)(sAh + wOff0) = vAh0; *(int4*)(sAh + wOff1) = vAh1;
    *(int4*)(sBh + wOff0) = vBh0; *(int4*)(sBh + wOff1) = vBh1;
    __syncthreads();

    bf16x8 afh[4], bfh[4];
#pragma unroll
    for (int mt = 0; mt < 4; ++mt) {
      const int rA = wr + (mt << 4) + fr;
      const int o = (rA << 5) + ((q ^ ((rA >> 1) & 3)) << 3);
      afh[mt] = *(const bf16x8*)(sAh + o);
    }
#pragma unroll
    for (int nt = 0; nt < 4; ++nt) {
      const int rB = wc + (nt << 4) + fr;
      const int o = (rB << 5) + ((q ^ ((rB >> 1) & 3)) << 3);
      bfh[nt] = *(const bf16x8*)(sBh + o);
    }
#pragma unroll
    for (int mt = 0; mt < 4; ++mt)
#pragma unroll
      for (int nt = 0; nt < 4; ++nt)
        acc[mt][nt] = __builtin_amdgcn_mfma_f32_16x16x32_bf16(afh[mt], bfh[nt], acc[mt][nt], 0, 0, 0);
  }

  const int quad = l >> 4;
#pragma unroll
  for (int mt = 0; mt < 4; ++mt) {
#pragma unroll
    for (int reg = 0; reg < 4; ++reg) {
      const int row = rowTile + wr + (mt << 4) + (quad << 2) + reg;
#pragma unroll
      for (int nt = 0; nt < 4; ++nt) {
        const int col = colTile + wc + (nt << 4) + fr;
        C[(size_t)row * KD + col] = acc[mt][nt][reg] + bias[col];
      }
    }
  }
}

// ---- LN + leaky -> influence(bf16); residual hi(bf16) + f32 + norms ----
__global__ __launch_bounds__(256) void ln_residual(
    const float* __restrict__ h, const float* __restrict__ g, const float* __restrict__ be,
    const float* __restrict__ z, const float* __restrict__ gRaw,
    __hip_bfloat16* __restrict__ infl, float* __restrict__ rn,
    __hip_bfloat16* __restrict__ rH, float* __restrict__ resF) {
  __shared__ float sred[4];
  const int row = blockIdx.x, t = threadIdx.x;
  const size_t base = (size_t)row * KD;
  float h0 = h[base + t], h1 = h[base + t + 256];
  float m = block_sum(h0 + h1, sred) * (1.0f / 512.0f);
  float d0 = h0 - m, d1 = h1 - m;
  float var = block_sum(d0 * d0 + d1 * d1, sred) * (1.0f / 512.0f);
  float sq = sqrtf(var + 1e-5f);
  float gc = sigmoidf_(gRaw[0]);
  float v0 = d0 / sq * g[t] + be[t];
  float v1 = d1 / sq * g[t + 256] + be[t + 256];
  v0 = v0 > 0.0f ? v0 : 0.1f * v0;
  v1 = v1 > 0.0f ? v1 : 0.1f * v1;
  infl[base + t] = __float2bfloat16(v0);
  infl[base + t + 256] = __float2bfloat16(v1);
  float zf0 = z[(size_t)row * 1024 + 512 + t];
  float zf1 = z[(size_t)row * 1024 + 512 + t + 256];
  float r0 = zf0 - gc * v0, r1 = zf1 - gc * v1;
  rH[base + t] = __float2bfloat16(r0);
  rH[base + t + 256] = __float2bfloat16(r1);
  resF[base + t] = r0;
  resF[base + t + 256] = r1;
  float rs = block_sum(r0 * r0 + r1 * r1, sred);
  if (t == 0) rn[row] = rs;
}

// ---- LN+leaky on h2, gather q_c/q_f, outputs + loss partials ----
__global__ __launch_bounds__(256) void finalize(
    const float* __restrict__ h, const float* __restrict__ g, const float* __restrict__ be,
    const __hip_bfloat16* __restrict__ infl,
    const u64* __restrict__ amc, const u64* __restrict__ amf,
    const float* __restrict__ z, const float* __restrict__ ce, const float* __restrict__ fe,
    const float* __restrict__ gcRaw, const float* __restrict__ gfRaw,
    float* __restrict__ out, float* __restrict__ lossp) {
  __shared__ float sred[4];
  const int row = blockIdx.x, t = threadIdx.x;
  const size_t base = (size_t)row * KD;
  float h0 = h[base + t], h1 = h[base + t + 256];
  float m = block_sum(h0 + h1, sred) * (1.0f / 512.0f);
  float d0 = h0 - m, d1 = h1 - m;
  float var = block_sum(d0 * d0 + d1 * d1, sred) * (1.0f / 512.0f);
  float sq = sqrtf(var + 1e-5f);
  float fb0 = d0 / sq * g[t] + be[t];
  float fb1 = d1 / sq * g[t + 256] + be[t + 256];
  fb0 = fb0 > 0.0f ? fb0 : 0.1f * fb0;
  fb1 = fb1 > 0.0f ? fb1 : 0.1f * fb1;
  float gc = sigmoidf_(gcRaw[0]);
  float gf = sigmoidf_(gfRaw[0]);
  unsigned ic = (unsigned)(amc[row] & 0xffffffffULL);
  unsigned ifx = (unsigned)(amf[row] & 0xffffffffULL);
  float loc = 0.0f;
#pragma unroll
  for (int j = 0; j < 2; ++j) {
    int c = t + j * 256;
    float fb = j ? fb1 : fb0;
    float qc = ce[(size_t)ic * KD + c];
    float qf = fe[(size_t)ifx * KD + c];
    float zc = z[(size_t)row * 1024 + c];
    float zf = z[(size_t)row * 1024 + 512 + c];
    float fl = __bfloat162float(infl[base + c]);
    out[(size_t)row * 1024 + c] = qc + 0.1f * gf * fb;
    out[(size_t)row * 1024 + 512 + c] = qf + gc * fl;
    float dc = qc - zc;
    float res = zf - gc * fl;
    float df = qf - res;
    loc += dc * dc + df * df;
  }
  float ls = block_sum(loc, sred);
  if (t == 0) atomicAdd(lossp, ls);
}

__global__ void loss_write(const float* __restrict__ lossp, float* __restrict__ out) {
  out[0] = 1.25f * lossp[0] / (8192.0f * 512.0f);
}

extern "C" void kernel_launch(void* const* d_in, const int* in_sizes, int n_in,
                              void* d_out, int out_size, void* d_ws, size_t ws_size,
                              hipStream_t stream) {
  const float* z      = (const float*)d_in[0];
  const float* ce     = (const float*)d_in[1];
  const float* fe     = (const float*)d_in[2];
  const float* w_c2f  = (const float*)d_in[3];
  const float* b_c2f  = (const float*)d_in[4];
  const float* g_c2f  = (const float*)d_in[5];
  const float* be_c2f = (const float*)d_in[6];
  const float* w_f2c  = (const float*)d_in[7];
  const float* b_f2c  = (const float*)d_in[8];
  const float* g_f2c  = (const float*)d_in[9];
  const float* be_f2c = (const float*)d_in[10];
  const float* gcRaw  = (const float*)d_in[11];
  const float* gfRaw  = (const float*)d_in[12];
  float* out = (float*)d_out;
  char* ws = (char*)d_ws;

  float* cn = (float*)(ws + OFF_CN);
  float* fn = (float*)(ws + OFF_FN);
  float* zn = (float*)(ws + OFF_ZN);
  float* rn = (float*)(ws + OFF_RN);
  float* lossp = (float*)(ws + OFF_LOSS);
  u64* amc = (u64*)(ws + OFF_AMC);
  u64* amf = (u64*)(ws + OFF_AMF);
  __hip_bfloat16* ceH = (__hip_bfloat16*)(ws + OFF_CEH);
  __hip_bfloat16* ceL = (__hip_bfloat16*)(ws + OFF_CEL);
  __hip_bfloat16* feH = (__hip_bfloat16*)(ws + OFF_FEH);
  __hip_bfloat16* feL = (__hip_bfloat16*)(ws + OFF_FEL);
  __hip_bfloat16* zcH = (__hip_bfloat16*)(ws + OFF_ZCH);
  __hip_bfloat16* rH  = (__hip_bfloat16*)(ws + OFF_RH);
  __hip_bfloat16* w1H = (__hip_bfloat16*)(ws + OFF_W1H);
  __hip_bfloat16* w1L = (__hip_bfloat16*)(ws + OFF_W1L);
  __hip_bfloat16* w2H = (__hip_bfloat16*)(ws + OFF_W2H);
  __hip_bfloat16* w2L = (__hip_bfloat16*)(ws + OFF_W2L);
  float* h = (float*)(ws + OFF_H);
  __hip_bfloat16* infl = (__hip_bfloat16*)(ws + OFF_INFL);
  u64* bkeys = (u64*)(ws + OFF_H);        // reused during VQ stages
  float* resF = (float*)(ws + OFF_ZCH);   // 16.78 MB, reuses zcH+zcL after coarse VQ

  // norms + splits (codebooks -> frag layout); zero loss
  prep<<<21504, 256, 0, stream>>>(ce, fe, z, w_c2f, w_f2c, cn, fn, zn,
                                  ceH, ceL, feH, feL, zcH,
                                  w1H, w1L, w2H, w2L, lossp);

  // coarse VQ approx: 4096 codes (16 y-tiles of 256) x 8192 queries
  vq10<<<dim3(64, 16), 256, 0, stream>>>((const int4*)ceH, zcH, cn, bkeys);

  // coarse rescue: exact f32 rescore (reference-matching arithmetic) -> amc
  rescue<<<2048, 256, 0, stream>>>(bkeys, 48, z, 1024, ce, zn, cn, 0.00321f, amc);

  // MLP1 (3-pass): h = gather(ce, amc) @ w_c2f^T + b
  mlp6<<<dim3(4, 64), 256, 0, stream>>>((const int4*)ceH, (const int4*)ceL, amc,
                                        w1H, w1L, b_c2f, h);

  // LN + leaky -> influence (bf16); residual hi + f32 + norms
  ln_residual<<<8192, 256, 0, stream>>>(h, g_c2f, be_c2f, z, gcRaw, infl, rn, rH, resF);

  // fine VQ approx: 8192 codes (32 y-tiles of 256) x 8192 queries
  vq10<<<dim3(64, 32), 256, 0, stream>>>((const int4*)feH, rH, fn, bkeys);

  // fine rescue -> amf
  rescue<<<2048, 256, 0, stream>>>(bkeys, 96, resF, 512, fe, rn, fn, 0.00233f, amf);

  // MLP2 (1-pass): h = gather(fe, amf) @ w_f2c^T + b
  mlp1p<<<dim3(4, 64), 256, 0, stream>>>((const int4*)feH, amf, w2H, b_f2c, h);

  // outputs + loss
  finalize<<<8192, 256, 0, stream>>>(h, g_f2c, be_f2c, infl, amc, amf, z, ce, fe,
                                     gcRaw, gfRaw, out, lossp);
  loss_write<<<1, 1, 0, stream>>>(lossp, out + (size_t)8192 * 1024);
}